// Round 15
// baseline (1172.746 us; speedup 1.0000x reference)
//
#include <hip/hip_runtime.h>

#define NN 40000
#define NE 320000
#define TT 4
#define SCAN_CHUNK 1024
#define NBLK_SCAN ((NN + SCAN_CHUNK - 1) / SCAN_CHUNK)  // 40

typedef unsigned short u16;

__device__ __forceinline__ float bcastf(float v, int k) {
    return __builtin_bit_cast(float, __builtin_amdgcn_readlane(__builtin_bit_cast(int, v), k));
}
__device__ __forceinline__ int bcasti(int v, int k) {
    return __builtin_amdgcn_readlane(v, k);
}
// bf16 <-> fp32 (RNE)
__device__ __forceinline__ float b2f(u16 u) {
    return __builtin_bit_cast(float, (unsigned)u << 16);
}
__device__ __forceinline__ u16 f2b(float f) {
    unsigned x = __builtin_bit_cast(unsigned, f);
    unsigned r = x + 0x7fffu + ((x >> 16) & 1u);
    return (u16)(r >> 16);
}
__device__ __forceinline__ float lo16(unsigned u) {
    return __builtin_bit_cast(float, u << 16);
}
__device__ __forceinline__ float hi16(unsigned u) {
    return __builtin_bit_cast(float, u & 0xffff0000u);
}

// ---------------- embedding: h = inputs @ W_emb (bf16 out) ----------------
__global__ void emb_kernel(const float* __restrict__ x, const float* __restrict__ W,
                           u16* __restrict__ h) {
    int i = blockIdx.x * blockDim.x + threadIdx.x;
    if (i >= NN * 64) return;
    int n = i >> 6, j = i & 63;
    float acc = 0.f;
#pragma unroll
    for (int k = 0; k < 16; ++k) acc = fmaf(x[n * 16 + k], W[k * 64 + j], acc);
    h[i] = f2b(acc);
}

// ---- Wfold[k][j] = Wp_e[0][k][j] + Wp_e[0][k+8][j] ----
__global__ void wfold_kernel(const float* __restrict__ We, float* __restrict__ Wf) {
    int i = threadIdx.x;
    if (i < 128) Wf[i] = We[i] + We[i + 128];
}

// ================= CSR build (once per launch) =================
__global__ void hist_kernel(const int* __restrict__ dst, int* __restrict__ deg) {
    int e = blockIdx.x * blockDim.x + threadIdx.x;
    if (e < NE) atomicAdd(&deg[dst[e]], 1);
}

__global__ void scan1_kernel(const int* __restrict__ deg, int* __restrict__ bsum) {
    __shared__ int sdata[256];
    int b = blockIdx.x, t = threadIdx.x;
    int base = b * SCAN_CHUNK;
    int sum = 0;
    for (int i = t; i < SCAN_CHUNK; i += 256) {
        int idx = base + i;
        sum += (idx < NN) ? deg[idx] : 0;
    }
    sdata[t] = sum;
    __syncthreads();
    for (int off = 128; off > 0; off >>= 1) {
        if (t < off) sdata[t] += sdata[t + off];
        __syncthreads();
    }
    if (t == 0) bsum[b] = sdata[0];
}

__global__ void scan2_kernel(const int* __restrict__ bsum, int* __restrict__ boff,
                             int* __restrict__ rowptr) {
    if (threadIdx.x == 0) {
        int acc = 0;
        for (int i = 0; i < NBLK_SCAN; ++i) {
            boff[i] = acc;
            acc += bsum[i];
        }
        rowptr[NN] = NE;
    }
}

__global__ void scan3_kernel(const int* __restrict__ deg, const int* __restrict__ boff,
                             int* __restrict__ rowptr, int* __restrict__ cursor) {
    __shared__ int ss[256];
    int b = blockIdx.x, t = threadIdx.x;
    int base = b * SCAN_CHUNK + t * 4;
    int v[4], s = 0;
#pragma unroll
    for (int q = 0; q < 4; ++q) {
        int idx = base + q;
        v[q] = (idx < NN) ? deg[idx] : 0;
        s += v[q];
    }
    ss[t] = s;
    __syncthreads();
    for (int off = 1; off < 256; off <<= 1) {
        int add = (t >= off) ? ss[t - off] : 0;
        __syncthreads();
        ss[t] += add;
        __syncthreads();
    }
    int excl = boff[b] + ss[t] - s;
#pragma unroll
    for (int q = 0; q < 4; ++q) {
        int idx = base + q;
        if (idx < NN) {
            rowptr[idx] = excl;
            cursor[idx] = excl;
        }
        excl += v[q];
    }
}

__global__ void scatter_kernel(const int* __restrict__ src, const int* __restrict__ dst,
                               int* __restrict__ cursor, int* __restrict__ perm,
                               int* __restrict__ srcp) {
    int e = blockIdx.x * blockDim.x + threadIdx.x;
    if (e >= NE) return;
    int d = dst[e];
    int pos = atomicAdd(&cursor[d], 1);
    perm[pos] = e;
    srcp[pos] = src[e];
}

// ---- degree counting-sort (descending): order[] = node IDs by deg bucket ----
__global__ void dhist_kernel(const int* __restrict__ rowptr, int* __restrict__ dh) {
    int n = blockIdx.x * blockDim.x + threadIdx.x;
    if (n >= NN) return;
    int d = rowptr[n + 1] - rowptr[n];
    if (d > 64) d = 64;
    atomicAdd(&dh[64 - d], 1);
}

__global__ void dscan_kernel(const int* __restrict__ dh, int* __restrict__ dcur) {
    if (threadIdx.x == 0) {
        int a = 0;
        for (int i = 0; i < 65; ++i) {
            dcur[i] = a;
            a += dh[i];
        }
    }
}

__global__ void dscatter_kernel(const int* __restrict__ rowptr, int* __restrict__ dcur,
                                int* __restrict__ order) {
    int n = blockIdx.x * blockDim.x + threadIdx.x;
    if (n >= NN) return;
    int d = rowptr[n + 1] - rowptr[n];
    if (d > 64) d = 64;
    int pos = atomicAdd(&dcur[64 - d], 1);
    order[pos] = n;
}

__global__ void efperm_all_kernel(const float* __restrict__ ef, const int* __restrict__ perm,
                                  u16* __restrict__ out) {
    int pos = blockIdx.x * blockDim.x + threadIdx.x;
    if (pos >= NE) return;
    int e = perm[pos];
    const float4* e4 = reinterpret_cast<const float4*>(ef) + (size_t)e * 8;
#pragma unroll
    for (int k = 0; k < 8; ++k) {
        float4 v = e4[k];
        out[0 * (size_t)NE * 8 + pos * 8 + k] = f2b(v.x);
        out[1 * (size_t)NE * 8 + pos * 8 + k] = f2b(v.y);
        out[2 * (size_t)NE * 8 + pos * 8 + k] = f2b(v.z);
        out[3 * (size_t)NE * 8 + pos * 8 + k] = f2b(v.w);
    }
}

__global__ void efperm_one_kernel(const float* __restrict__ ef, const int* __restrict__ perm,
                                  int t, u16* __restrict__ out) {
    int i = blockIdx.x * blockDim.x + threadIdx.x;
    if (i >= NE * 8) return;
    int pos = i >> 3, k = i & 7;
    int e = perm[pos];
    out[i] = f2b(ef[((size_t)e * 8 + k) * 4 + t]);
}

// ================= node transforms (R13-proven) =================
__global__ __launch_bounds__(256) void node_ab_kernel(
    const u16* __restrict__ X1, int relu1,
    const float* __restrict__ X2, int d2,
    const float* __restrict__ Whs, const float* __restrict__ Whd,
    const float* __restrict__ rain, const float* __restrict__ Wr,
    u16* __restrict__ A, u16* __restrict__ B) {
    extern __shared__ float sW[];
    const int dtot = 64 + d2;
    float* sWs = sW;
    float* sWd = sW + (dtot << 6);
    for (int i = threadIdx.x; i < (dtot << 6); i += 256) {
        sWs[i] = Whs[i];
        sWd[i] = Whd[i];
    }
    __syncthreads();
    const int lane = threadIdx.x & 63;
    const int wid = (blockIdx.x << 2) + (threadIdx.x >> 6);
    const int n0 = wid << 3;
    const float wr = Wr[lane];
    float xv[8], aa[8], bb[8];
#pragma unroll
    for (int p = 0; p < 8; ++p) {
        float x = b2f(__builtin_nontemporal_load(&X1[(size_t)(n0 + p) * 64 + lane]));
        xv[p] = relu1 ? fmaxf(x, 0.f) : x;
        aa[p] = rain[(n0 + p) * TT] * wr;
        bb[p] = 0.f;
    }
#pragma unroll 16
    for (int k = 0; k < 64; ++k) {
        float ws = sWs[(k << 6) + lane];
        float wd = sWd[(k << 6) + lane];
#pragma unroll
        for (int p = 0; p < 8; ++p) {
            float xk = bcastf(xv[p], k);
            aa[p] = fmaf(xk, ws, aa[p]);
            bb[p] = fmaf(xk, wd, bb[p]);
        }
    }
    if (d2) {
#pragma unroll
        for (int p = 0; p < 8; ++p) xv[p] = X2[(n0 + p) * 16 + (lane & 15)];
#pragma unroll
        for (int k = 0; k < 16; ++k) {
            float ws = sWs[((64 + k) << 6) + lane];
            float wd = sWd[((64 + k) << 6) + lane];
#pragma unroll
            for (int p = 0; p < 8; ++p) {
                float xk = bcastf(xv[p], k);
                aa[p] = fmaf(xk, ws, aa[p]);
                bb[p] = fmaf(xk, wd, bb[p]);
            }
        }
    }
#pragma unroll
    for (int p = 0; p < 8; ++p) {
        A[(size_t)(n0 + p) * 64 + lane] = f2b(aa[p]);
        B[(size_t)(n0 + p) * 64 + lane] = f2b(bb[p]);
    }
}

__global__ __launch_bounds__(256) void node_p_all(
    const u16* __restrict__ X,
    const float* __restrict__ Whs, const float* __restrict__ Whd,
    const float* __restrict__ rain, const float* __restrict__ Wr,
    float* __restrict__ Ap0, float* __restrict__ Bp0,
    float* __restrict__ Ap1, float* __restrict__ Bp1) {
    __shared__ float sX[64 * 68];
    __shared__ float sW[4][1024];
    for (int i = threadIdx.x; i < 1024; i += 256) {
        sW[0][i] = Whs[i];
        sW[1][i] = Whd[i];
        sW[2][i] = Whs[1024 + i];
        sW[3][i] = Whd[1024 + i];
    }
    const int n0 = blockIdx.x << 6;
    for (int i = threadIdx.x; i < 512; i += 256) {
        int row = i >> 3, col = (i & 7) << 3;
        uint4 v = *reinterpret_cast<const uint4*>(&X[(size_t)(n0 + row) * 64 + col]);
        float* d = &sX[row * 68 + col];
        d[0] = fmaxf(lo16(v.x), 0.f);
        d[1] = fmaxf(hi16(v.x), 0.f);
        d[2] = fmaxf(lo16(v.y), 0.f);
        d[3] = fmaxf(hi16(v.y), 0.f);
        d[4] = fmaxf(lo16(v.z), 0.f);
        d[5] = fmaxf(hi16(v.z), 0.f);
        d[6] = fmaxf(lo16(v.w), 0.f);
        d[7] = fmaxf(hi16(v.w), 0.f);
    }
    __syncthreads();
    const int j = threadIdx.x & 15;
    const int nl0 = threadIdx.x >> 4;
    const float wr0 = Wr[j], wr1 = Wr[16 + j];
    float a0[4], b0[4], a1[4], b1[4];
#pragma unroll
    for (int q = 0; q < 4; ++q) {
        float rn = rain[(n0 + nl0 + (q << 4)) * TT];
        a0[q] = rn * wr0;
        a1[q] = rn * wr1;
        b0[q] = 0.f;
        b1[q] = 0.f;
    }
#pragma unroll 4
    for (int k = 0; k < 64; ++k) {
        float wa0 = sW[0][(k << 4) + j], wb0 = sW[1][(k << 4) + j];
        float wa1 = sW[2][(k << 4) + j], wb1 = sW[3][(k << 4) + j];
#pragma unroll
        for (int q = 0; q < 4; ++q) {
            float x = sX[(nl0 + (q << 4)) * 68 + k];
            a0[q] = fmaf(x, wa0, a0[q]);
            b0[q] = fmaf(x, wb0, b0[q]);
            a1[q] = fmaf(x, wa1, a1[q]);
            b1[q] = fmaf(x, wb1, b1[q]);
        }
    }
#pragma unroll
    for (int q = 0; q < 4; ++q) {
        int n = n0 + nl0 + (q << 4);
        Ap0[n * 16 + j] = a0[q];
        Bp0[n * 16 + j] = b0[q];
        Ap1[n * 16 + j] = a1[q];
        Bp1[n * 16 + j] = b1[q];
    }
}

// ================= CSR edge passes =================
// 64-wide (R13-proven loop), wave per dst node taken from degree-sorted order[].
// Grid = 10000 blocks. bcasti legal: wave owns one row (kk wave-uniform).
__global__ __launch_bounds__(256) void edge64_csr(
    const u16* __restrict__ A, const u16* __restrict__ B,
    const u16* __restrict__ efp, const float* __restrict__ We,
    const int* __restrict__ rowptr, const int* __restrict__ srcp,
    const int* __restrict__ order,
    u16* __restrict__ agg, const float* __restrict__ Wrain,
    float* __restrict__ out, int t) {
    const int lane = threadIdx.x & 63;
    const int n = order[(blockIdx.x << 2) + (threadIdx.x >> 6)];
    const float w0 = We[lane], w1 = We[64 + lane];
    const float w2 = We[128 + lane], w3 = We[192 + lane];
    const float w4 = We[256 + lane], w5 = We[320 + lane];
    const float w6 = We[384 + lane], w7 = We[448 + lane];
    const int beg = rowptr[n], end = rowptr[n + 1];
    const int deg = end - beg;
    int sv = 0;
    if (beg + lane < NE) sv = srcp[beg + lane];
    const float b = b2f(__builtin_nontemporal_load(&B[(size_t)n * 64 + lane]));
    const uint4* ef4 = reinterpret_cast<const uint4*>(efp);
    float acc = 0.f;
    for (int k0 = 0; k0 < deg; k0 += 4) {
        u16 av[4];
        uint4 ev[4];
#pragma unroll
        for (int i = 0; i < 4; ++i) {
            int kk = k0 + i;
            if (kk > deg - 1) kk = deg - 1;  // clamped duplicate; masked in consume
            int s = (kk < 64) ? bcasti(sv, kk) : srcp[beg + kk];
            av[i] = A[(size_t)s * 64 + lane];
            ev[i] = ef4[(size_t)(beg + kk)];
        }
#pragma unroll
        for (int i = 0; i < 4; ++i) {
            if (k0 + i < deg) {
                float m = b2f(av[i]) + b;
                m = fmaf(lo16(ev[i].x), w0, m);
                m = fmaf(hi16(ev[i].x), w1, m);
                m = fmaf(lo16(ev[i].y), w2, m);
                m = fmaf(hi16(ev[i].y), w3, m);
                m = fmaf(lo16(ev[i].z), w4, m);
                m = fmaf(hi16(ev[i].z), w5, m);
                m = fmaf(lo16(ev[i].w), w6, m);
                m = fmaf(hi16(ev[i].w), w7, m);
                acc += fmaxf(m, 0.f);
            }
        }
    }
    __builtin_nontemporal_store(f2b(acc), &agg[(size_t)n * 64 + lane]);
    if (out) {
        float r = fmaxf(acc, 0.f) * Wrain[lane];
#pragma unroll
        for (int off = 32; off > 0; off >>= 1) r += __shfl_down(r, off);
        if (lane == 0) out[n * TT + t] = r;
    }
}

// 16-wide edge pass (R11-proven loop), rows taken from degree-sorted order[].
__global__ __launch_bounds__(256) void edge16_csr(
    const float* __restrict__ G, const float* __restrict__ Bp,
    const u16* __restrict__ efp, const float* __restrict__ Wf, int has_ef,
    const float* __restrict__ ApN, const float* __restrict__ WeN,
    float* __restrict__ PeSN, int has_epi,
    const int* __restrict__ rowptr, const int* __restrict__ srcp,
    const int* __restrict__ order,
    float* __restrict__ pout) {
    const int lane = threadIdx.x & 63;
    const int g = lane >> 4, j = lane & 15;
    float w[8];
    if (has_ef) {
#pragma unroll
        for (int k = 0; k < 8; ++k) w[k] = Wf[k * 16 + j];
    }
    const int wid = (blockIdx.x * 256 + threadIdx.x) >> 6;
    const int n = order[(wid << 2) + g];
    const int beg = rowptr[n], end = rowptr[n + 1];
    const float b = Bp[n * 16 + j];
    const uint4* ef4 = reinterpret_cast<const uint4*>(efp);
    float acc = 0.f;
    int s_nxt = (beg + 1 < end) ? srcp[beg + 1] : 0;
    float av = (beg < end) ? G[srcp[beg] * 16 + j] : 0.f;
    for (int pos = beg; pos < end; ++pos) {
        float avc = av;
        int s_nn = (pos + 2 < end) ? srcp[pos + 2] : 0;
        if (pos + 1 < end) av = G[s_nxt * 16 + j];
        s_nxt = s_nn;
        float m = avc + b;
        if (has_ef) {
            uint4 ev = ef4[(size_t)pos];
            m = fmaf(lo16(ev.x), w[0], m);
            m = fmaf(hi16(ev.x), w[1], m);
            m = fmaf(lo16(ev.y), w[2], m);
            m = fmaf(hi16(ev.y), w[3], m);
            m = fmaf(lo16(ev.z), w[4], m);
            m = fmaf(hi16(ev.z), w[5], m);
            m = fmaf(lo16(ev.w), w[6], m);
            m = fmaf(hi16(ev.w), w[7], m);
        }
        acc += fmaxf(m, 0.f);
    }
    if (pout) pout[n * 16 + j] = acc;
    if (has_epi) {
        float pe = ApN[n * 16 + j];
        const int gbase = lane & 48;
#pragma unroll
        for (int k = 0; k < 16; ++k) {
            float pk = __shfl(acc, gbase + k);
            pe = fmaf(pk, WeN[k * 16 + j], pe);
        }
        PeSN[n * 16 + j] = pe;
    }
}

extern "C" void kernel_launch(void* const* d_in, const int* in_sizes, int n_in,
                              void* d_out, int out_size, void* d_ws, size_t ws_size,
                              hipStream_t stream) {
    (void)in_sizes; (void)n_in; (void)out_size;
    const float* inputs = (const float*)d_in[0];
    const float* e_feats = (const float*)d_in[1];
    const float* rain0 = (const float*)d_in[2];
    const int* src = (const int*)d_in[3];
    const int* dst = (const int*)d_in[4];
    const float* W_emb = (const float*)d_in[5];
    const float* Win_hs = (const float*)d_in[6];
    const float* Win_hd = (const float*)d_in[7];
    const float* Win_e = (const float*)d_in[8];
    const float* Win_r = (const float*)d_in[9];
    const float* Wp_hs = (const float*)d_in[10];
    const float* Wp_hd = (const float*)d_in[11];
    const float* Wp_e = (const float*)d_in[12];
    const float* Wp_r = (const float*)d_in[13];
    const float* Wo_hs = (const float*)d_in[14];
    const float* Wo_hd = (const float*)d_in[15];
    const float* Wo_e = (const float*)d_in[16];
    const float* Wo_r = (const float*)d_in[17];
    const float* W_rain = (const float*)d_in[18];
    float* out = (float*)d_out;

    const size_t NF64 = (size_t)NN * 64;
    const size_t NF16 = (size_t)NN * 16;
    const size_t EF = (size_t)NE * 8;

    char* base = (char*)d_ws;
    auto alloc = [&](size_t bytes) -> char* {
        char* p = base;
        base += (bytes + 255) & ~(size_t)255;
        return p;
    };

    const size_t fixed = 5 * NF64 * 2 + 7 * NF16 * 4 +
                         (2 * (size_t)NE + 4 * (size_t)NN + 400) * 4 + 64 * 256;
    const bool big = ws_size >= fixed + 4 * EF * 2;

    u16 *A16, *B16, *aggA16, *aggB16, *aggO16, *efp16;
    float *Ap0, *Bp0, *Ap1, *Bp1, *PeSa, *PeSb, *pbuf, *Wfold;
    A16 = (u16*)alloc(NF64 * 2);
    B16 = (u16*)alloc(NF64 * 2);
    aggA16 = (u16*)alloc(NF64 * 2);
    aggB16 = (u16*)alloc(NF64 * 2);
    aggO16 = (u16*)alloc(NF64 * 2);
    Ap0 = (float*)alloc(NF16 * 4);
    Bp0 = (float*)alloc(NF16 * 4);
    Ap1 = (float*)alloc(NF16 * 4);
    Bp1 = (float*)alloc(NF16 * 4);
    PeSa = (float*)alloc(NF16 * 4);
    PeSb = (float*)alloc(NF16 * 4);
    pbuf = (float*)alloc(NF16 * 4);
    Wfold = (float*)alloc(128 * 4);
    efp16 = (u16*)alloc((big ? 4 * EF : EF) * 2);
    int* srcp = (int*)alloc(NE * 4);
    int* perm = (int*)alloc(NE * 4);
    int* rowptr = (int*)alloc((NN + 1) * 4);
    int* deg = (int*)alloc(NN * 4);
    int* cursor = (int*)alloc(NN * 4);
    int* order = (int*)alloc(NN * 4);
    int* bsum = (int*)alloc(64 * 4);
    int* boff = (int*)alloc(64 * 4);
    int* dh = (int*)alloc(65 * 4);
    int* dcur = (int*)alloc(65 * 4);
    u16* hemb = aggO16;  // safe alias: aggO16 written only at end of t=0

    // ---- CSR build + degree sort (once) ----
    hipMemsetAsync(deg, 0, NN * sizeof(int), stream);
    hipMemsetAsync(dh, 0, 65 * sizeof(int), stream);
    hist_kernel<<<(NE + 255) / 256, 256, 0, stream>>>(dst, deg);
    scan1_kernel<<<NBLK_SCAN, 256, 0, stream>>>(deg, bsum);
    scan2_kernel<<<1, 64, 0, stream>>>(bsum, boff, rowptr);
    scan3_kernel<<<NBLK_SCAN, 256, 0, stream>>>(deg, boff, rowptr, cursor);
    scatter_kernel<<<(NE + 255) / 256, 256, 0, stream>>>(src, dst, cursor, perm, srcp);
    dhist_kernel<<<(NN + 255) / 256, 256, 0, stream>>>(rowptr, dh);
    dscan_kernel<<<1, 64, 0, stream>>>(dh, dcur);
    dscatter_kernel<<<(NN + 255) / 256, 256, 0, stream>>>(rowptr, dcur, order);
    if (big)
        efperm_all_kernel<<<(NE + 255) / 256, 256, 0, stream>>>(e_feats, perm, efp16);

    emb_kernel<<<(NN * 64 + 255) / 256, 256, 0, stream>>>(inputs, W_emb, hemb);
    wfold_kernel<<<1, 128, 0, stream>>>(Wp_e, Wfold);

    for (int t = 0; t < TT; ++t) {
        const float* rain = rain0 + t;
        const u16* eft = big ? (efp16 + (size_t)t * EF) : efp16;
        if (!big)
            efperm_one_kernel<<<(NE * 8 + 255) / 256, 256, 0, stream>>>(e_feats, perm, t, efp16);

        // ---- IN s=0 ----
        node_ab_kernel<<<1250, 256, 64 * 64 * 2 * sizeof(float), stream>>>(
            aggO16, (t > 0) ? 1 : 0, nullptr, 0,
            Win_hs, Win_hd, rain, Win_r, A16, B16);
        edge64_csr<<<10000, 256, 0, stream>>>(A16, B16, eft, Win_e, rowptr, srcp, order,
                                              aggA16, nullptr, nullptr, 0);

        // ---- IN s=1 ----
        node_ab_kernel<<<1250, 256, 64 * 64 * 2 * sizeof(float), stream>>>(
            aggA16, 1, nullptr, 0, Win_hs + 4096, Win_hd + 4096, rain, Win_r + 64, A16, B16);
        edge64_csr<<<10000, 256, 0, stream>>>(A16, B16, eft, Win_e + 512, rowptr, srcp, order,
                                              aggB16, nullptr, nullptr, 0);

        // ---- PROP: p-independent node parts for both s in one pass ----
        node_p_all<<<625, 256, 0, stream>>>(aggB16, Wp_hs, Wp_hd, rain, Wp_r,
                                            Ap0, Bp0, Ap1, Bp1);

        if (t == 0) {
            edge16_csr<<<2500, 256, 0, stream>>>(Ap0, Bp0, eft, Wfold, 1,
                                                 Ap0, Wp_e, PeSa, 1,
                                                 rowptr, srcp, order, nullptr);
            edge16_csr<<<2500, 256, 0, stream>>>(PeSa, Bp0, nullptr, nullptr, 0,
                                                 Ap1, Wp_e + 256, PeSb, 1,
                                                 rowptr, srcp, order, nullptr);
            edge16_csr<<<2500, 256, 0, stream>>>(PeSb, Bp1, nullptr, nullptr, 0,
                                                 nullptr, nullptr, nullptr, 0,
                                                 rowptr, srcp, order, pbuf);
        } else {
            edge16_csr<<<2500, 256, 0, stream>>>(Ap0, Bp0, eft, Wfold, 1,
                                                 Ap1, Wp_e + 256, PeSa, 1,
                                                 rowptr, srcp, order, nullptr);
            edge16_csr<<<2500, 256, 0, stream>>>(PeSa, Bp1, nullptr, nullptr, 0,
                                                 nullptr, nullptr, nullptr, 0,
                                                 rowptr, srcp, order, pbuf);
        }

        // ---- OUT layer (fused rain-output epilogue) ----
        node_ab_kernel<<<1250, 256, 80 * 64 * 2 * sizeof(float), stream>>>(
            aggB16, 1, pbuf, 16, Wo_hs, Wo_hd, rain, Wo_r, A16, B16);
        edge64_csr<<<10000, 256, 0, stream>>>(A16, B16, eft, Wo_e, rowptr, srcp, order,
                                              aggO16, W_rain, out, t);
    }
}

// Round 16
// 952.831 us; speedup vs baseline: 1.2308x; 1.2308x over previous
//
#include <hip/hip_runtime.h>

#define NN 40000
#define NE 320000
#define TT 4
#define SCAN_CHUNK 1024
#define NBLK_SCAN ((NN + SCAN_CHUNK - 1) / SCAN_CHUNK)  // 40

typedef unsigned short u16;

__device__ __forceinline__ float bcastf(float v, int k) {
    return __builtin_bit_cast(float, __builtin_amdgcn_readlane(__builtin_bit_cast(int, v), k));
}
__device__ __forceinline__ int bcasti(int v, int k) {
    return __builtin_amdgcn_readlane(v, k);
}
// bf16 <-> fp32 (RNE)
__device__ __forceinline__ float b2f(u16 u) {
    return __builtin_bit_cast(float, (unsigned)u << 16);
}
__device__ __forceinline__ u16 f2b(float f) {
    unsigned x = __builtin_bit_cast(unsigned, f);
    unsigned r = x + 0x7fffu + ((x >> 16) & 1u);
    return (u16)(r >> 16);
}
__device__ __forceinline__ float lo16(unsigned u) {
    return __builtin_bit_cast(float, u << 16);
}
__device__ __forceinline__ float hi16(unsigned u) {
    return __builtin_bit_cast(float, u & 0xffff0000u);
}

// ---------------- embedding: h = inputs @ W_emb (bf16 out) ----------------
__global__ void emb_kernel(const float* __restrict__ x, const float* __restrict__ W,
                           u16* __restrict__ h) {
    int i = blockIdx.x * blockDim.x + threadIdx.x;
    if (i >= NN * 64) return;
    int n = i >> 6, j = i & 63;
    float acc = 0.f;
#pragma unroll
    for (int k = 0; k < 16; ++k) acc = fmaf(x[n * 16 + k], W[k * 64 + j], acc);
    h[i] = f2b(acc);
}

// ---- Wfold[k][j] = Wp_e[0][k][j] + Wp_e[0][k+8][j] ----
__global__ void wfold_kernel(const float* __restrict__ We, float* __restrict__ Wf) {
    int i = threadIdx.x;
    if (i < 128) Wf[i] = We[i] + We[i + 128];
}

// ================= CSR build (once per launch) =================
__global__ void hist_kernel(const int* __restrict__ dst, int* __restrict__ deg) {
    int e = blockIdx.x * blockDim.x + threadIdx.x;
    if (e < NE) atomicAdd(&deg[dst[e]], 1);
}

__global__ void scan1_kernel(const int* __restrict__ deg, int* __restrict__ bsum) {
    __shared__ int sdata[256];
    int b = blockIdx.x, t = threadIdx.x;
    int base = b * SCAN_CHUNK;
    int sum = 0;
    for (int i = t; i < SCAN_CHUNK; i += 256) {
        int idx = base + i;
        sum += (idx < NN) ? deg[idx] : 0;
    }
    sdata[t] = sum;
    __syncthreads();
    for (int off = 128; off > 0; off >>= 1) {
        if (t < off) sdata[t] += sdata[t + off];
        __syncthreads();
    }
    if (t == 0) bsum[b] = sdata[0];
}

__global__ void scan2_kernel(const int* __restrict__ bsum, int* __restrict__ boff,
                             int* __restrict__ rowptr) {
    if (threadIdx.x == 0) {
        int acc = 0;
        for (int i = 0; i < NBLK_SCAN; ++i) {
            boff[i] = acc;
            acc += bsum[i];
        }
        rowptr[NN] = NE;
    }
}

__global__ void scan3_kernel(const int* __restrict__ deg, const int* __restrict__ boff,
                             int* __restrict__ rowptr, int* __restrict__ cursor) {
    __shared__ int ss[256];
    int b = blockIdx.x, t = threadIdx.x;
    int base = b * SCAN_CHUNK + t * 4;
    int v[4], s = 0;
#pragma unroll
    for (int q = 0; q < 4; ++q) {
        int idx = base + q;
        v[q] = (idx < NN) ? deg[idx] : 0;
        s += v[q];
    }
    ss[t] = s;
    __syncthreads();
    for (int off = 1; off < 256; off <<= 1) {
        int add = (t >= off) ? ss[t - off] : 0;
        __syncthreads();
        ss[t] += add;
        __syncthreads();
    }
    int excl = boff[b] + ss[t] - s;
#pragma unroll
    for (int q = 0; q < 4; ++q) {
        int idx = base + q;
        if (idx < NN) {
            rowptr[idx] = excl;
            cursor[idx] = excl;
        }
        excl += v[q];
    }
}

__global__ void scatter_kernel(const int* __restrict__ src, const int* __restrict__ dst,
                               int* __restrict__ cursor, int* __restrict__ perm,
                               int* __restrict__ srcp) {
    int e = blockIdx.x * blockDim.x + threadIdx.x;
    if (e >= NE) return;
    int d = dst[e];
    int pos = atomicAdd(&cursor[d], 1);
    perm[pos] = e;
    srcp[pos] = src[e];
}

__global__ void efperm_all_kernel(const float* __restrict__ ef, const int* __restrict__ perm,
                                  u16* __restrict__ out) {
    int pos = blockIdx.x * blockDim.x + threadIdx.x;
    if (pos >= NE) return;
    int e = perm[pos];
    const float4* e4 = reinterpret_cast<const float4*>(ef) + (size_t)e * 8;
#pragma unroll
    for (int k = 0; k < 8; ++k) {
        float4 v = e4[k];
        out[0 * (size_t)NE * 8 + pos * 8 + k] = f2b(v.x);
        out[1 * (size_t)NE * 8 + pos * 8 + k] = f2b(v.y);
        out[2 * (size_t)NE * 8 + pos * 8 + k] = f2b(v.z);
        out[3 * (size_t)NE * 8 + pos * 8 + k] = f2b(v.w);
    }
}

__global__ void efperm_one_kernel(const float* __restrict__ ef, const int* __restrict__ perm,
                                  int t, u16* __restrict__ out) {
    int i = blockIdx.x * blockDim.x + threadIdx.x;
    if (i >= NE * 8) return;
    int pos = i >> 3, k = i & 7;
    int e = perm[pos];
    out[i] = f2b(ef[((size_t)e * 8 + k) * 4 + t]);
}

// ================= node transforms =================
// 64-wide: A = relu?(X1)@Whs (+X2@Whs[64:]) + rain*Wr, B likewise.
// X1 is bf16; bf16 outputs. 8 nodes/wave; grid must be 1250 blocks.
__global__ __launch_bounds__(256) void node_ab_kernel(
    const u16* __restrict__ X1, int relu1,
    const float* __restrict__ X2, int d2,
    const float* __restrict__ Whs, const float* __restrict__ Whd,
    const float* __restrict__ rain, const float* __restrict__ Wr,
    u16* __restrict__ A, u16* __restrict__ B) {
    extern __shared__ float sW[];
    const int dtot = 64 + d2;
    float* sWs = sW;
    float* sWd = sW + (dtot << 6);
    for (int i = threadIdx.x; i < (dtot << 6); i += 256) {
        sWs[i] = Whs[i];
        sWd[i] = Whd[i];
    }
    __syncthreads();
    const int lane = threadIdx.x & 63;
    const int wid = (blockIdx.x << 2) + (threadIdx.x >> 6);
    const int n0 = wid << 3;
    const float wr = Wr[lane];
    float xv[8], aa[8], bb[8];
#pragma unroll
    for (int p = 0; p < 8; ++p) {
        float x = b2f(__builtin_nontemporal_load(&X1[(size_t)(n0 + p) * 64 + lane]));
        xv[p] = relu1 ? fmaxf(x, 0.f) : x;
        aa[p] = rain[(n0 + p) * TT] * wr;
        bb[p] = 0.f;
    }
#pragma unroll 16
    for (int k = 0; k < 64; ++k) {
        float ws = sWs[(k << 6) + lane];
        float wd = sWd[(k << 6) + lane];
#pragma unroll
        for (int p = 0; p < 8; ++p) {
            float xk = bcastf(xv[p], k);
            aa[p] = fmaf(xk, ws, aa[p]);
            bb[p] = fmaf(xk, wd, bb[p]);
        }
    }
    if (d2) {
#pragma unroll
        for (int p = 0; p < 8; ++p) xv[p] = X2[(n0 + p) * 16 + (lane & 15)];
#pragma unroll
        for (int k = 0; k < 16; ++k) {
            float ws = sWs[((64 + k) << 6) + lane];
            float wd = sWd[((64 + k) << 6) + lane];
#pragma unroll
            for (int p = 0; p < 8; ++p) {
                float xk = bcastf(xv[p], k);
                aa[p] = fmaf(xk, ws, aa[p]);
                bb[p] = fmaf(xk, wd, bb[p]);
            }
        }
    }
#pragma unroll
    for (int p = 0; p < 8; ++p) {
        A[(size_t)(n0 + p) * 64 + lane] = f2b(aa[p]);
        B[(size_t)(n0 + p) * 64 + lane] = f2b(bb[p]);
    }
}

// prop node transform for BOTH scale steps (p-independent parts). X is bf16.
// Grid must be 625 blocks. fp32 outputs (small, L2-resident).
__global__ __launch_bounds__(256) void node_p_all(
    const u16* __restrict__ X,
    const float* __restrict__ Whs, const float* __restrict__ Whd,  // [2*64*16]
    const float* __restrict__ rain, const float* __restrict__ Wr,  // [2*16]
    float* __restrict__ Ap0, float* __restrict__ Bp0,
    float* __restrict__ Ap1, float* __restrict__ Bp1) {
    __shared__ float sX[64 * 68];
    __shared__ float sW[4][1024];
    for (int i = threadIdx.x; i < 1024; i += 256) {
        sW[0][i] = Whs[i];
        sW[1][i] = Whd[i];
        sW[2][i] = Whs[1024 + i];
        sW[3][i] = Whd[1024 + i];
    }
    const int n0 = blockIdx.x << 6;
    // stage 64 rows x 64 bf16: 512 chunks of 8 bf16 (uint4)
    for (int i = threadIdx.x; i < 512; i += 256) {
        int row = i >> 3, col = (i & 7) << 3;
        uint4 v = *reinterpret_cast<const uint4*>(&X[(size_t)(n0 + row) * 64 + col]);
        float* d = &sX[row * 68 + col];
        d[0] = fmaxf(lo16(v.x), 0.f);
        d[1] = fmaxf(hi16(v.x), 0.f);
        d[2] = fmaxf(lo16(v.y), 0.f);
        d[3] = fmaxf(hi16(v.y), 0.f);
        d[4] = fmaxf(lo16(v.z), 0.f);
        d[5] = fmaxf(hi16(v.z), 0.f);
        d[6] = fmaxf(lo16(v.w), 0.f);
        d[7] = fmaxf(hi16(v.w), 0.f);
    }
    __syncthreads();
    const int j = threadIdx.x & 15;
    const int nl0 = threadIdx.x >> 4;
    const float wr0 = Wr[j], wr1 = Wr[16 + j];
    float a0[4], b0[4], a1[4], b1[4];
#pragma unroll
    for (int q = 0; q < 4; ++q) {
        float rn = rain[(n0 + nl0 + (q << 4)) * TT];
        a0[q] = rn * wr0;
        a1[q] = rn * wr1;
        b0[q] = 0.f;
        b1[q] = 0.f;
    }
#pragma unroll 4
    for (int k = 0; k < 64; ++k) {
        float wa0 = sW[0][(k << 4) + j], wb0 = sW[1][(k << 4) + j];
        float wa1 = sW[2][(k << 4) + j], wb1 = sW[3][(k << 4) + j];
#pragma unroll
        for (int q = 0; q < 4; ++q) {
            float x = sX[(nl0 + (q << 4)) * 68 + k];
            a0[q] = fmaf(x, wa0, a0[q]);
            b0[q] = fmaf(x, wb0, b0[q]);
            a1[q] = fmaf(x, wa1, a1[q]);
            b1[q] = fmaf(x, wb1, b1[q]);
        }
    }
#pragma unroll
    for (int q = 0; q < 4; ++q) {
        int n = n0 + nl0 + (q << 4);
        Ap0[n * 16 + j] = a0[q];
        Bp0[n * 16 + j] = b0[q];
        Ap1[n * 16 + j] = a1[q];
        Bp1[n * 16 + j] = b1[q];
    }
}

// ================= CSR edge passes =================
// 64-wide, bf16 A/B/ef, bf16 agg out. Wave per dst node; srcp staged
// in-register; 4 gathers in flight. Grid = 10000 blocks.
// bcasti legal ONLY because the wave owns one row (kk wave-uniform).
__global__ __launch_bounds__(256) void edge64_csr(
    const u16* __restrict__ A, const u16* __restrict__ B,
    const u16* __restrict__ efp, const float* __restrict__ We,
    const int* __restrict__ rowptr, const int* __restrict__ srcp,
    u16* __restrict__ agg, const float* __restrict__ Wrain,
    float* __restrict__ out, int t) {
    const int lane = threadIdx.x & 63;
    const int n = (blockIdx.x << 2) + (threadIdx.x >> 6);
    const float w0 = We[lane], w1 = We[64 + lane];
    const float w2 = We[128 + lane], w3 = We[192 + lane];
    const float w4 = We[256 + lane], w5 = We[320 + lane];
    const float w6 = We[384 + lane], w7 = We[448 + lane];
    const int beg = rowptr[n], end = rowptr[n + 1];
    const int deg = end - beg;
    int sv = 0;
    if (beg + lane < NE) sv = srcp[beg + lane];
    const float b = b2f(__builtin_nontemporal_load(&B[(size_t)n * 64 + lane]));
    const uint4* ef4 = reinterpret_cast<const uint4*>(efp);
    float acc = 0.f;
    for (int k0 = 0; k0 < deg; k0 += 4) {
        u16 av[4];
        uint4 ev[4];
#pragma unroll
        for (int i = 0; i < 4; ++i) {
            int kk = k0 + i;
            if (kk > deg - 1) kk = deg - 1;  // clamped duplicate; masked in consume
            int s = (kk < 64) ? bcasti(sv, kk) : srcp[beg + kk];
            av[i] = A[(size_t)s * 64 + lane];
            ev[i] = ef4[(size_t)(beg + kk)];
        }
#pragma unroll
        for (int i = 0; i < 4; ++i) {
            if (k0 + i < deg) {
                float m = b2f(av[i]) + b;
                m = fmaf(lo16(ev[i].x), w0, m);
                m = fmaf(hi16(ev[i].x), w1, m);
                m = fmaf(lo16(ev[i].y), w2, m);
                m = fmaf(hi16(ev[i].y), w3, m);
                m = fmaf(lo16(ev[i].z), w4, m);
                m = fmaf(hi16(ev[i].z), w5, m);
                m = fmaf(lo16(ev[i].w), w6, m);
                m = fmaf(hi16(ev[i].w), w7, m);
                acc += fmaxf(m, 0.f);
            }
        }
    }
    __builtin_nontemporal_store(f2b(acc), &agg[(size_t)n * 64 + lane]);
    if (out) {
        float r = fmaxf(acc, 0.f) * Wrain[lane];
#pragma unroll
        for (int off = 32; off > 0; off >>= 1) r += __shfl_down(r, off);
        if (lane == 0) out[n * TT + t] = r;
    }
}

// ================= 16-wide edge pass (R11-proven) =================
__global__ __launch_bounds__(256) void edge16_csr(
    const float* __restrict__ G, const float* __restrict__ Bp,
    const u16* __restrict__ efp, const float* __restrict__ Wf, int has_ef,
    const float* __restrict__ ApN, const float* __restrict__ WeN,
    float* __restrict__ PeSN, int has_epi,
    const int* __restrict__ rowptr, const int* __restrict__ srcp,
    float* __restrict__ pout) {
    const int lane = threadIdx.x & 63;
    const int g = lane >> 4, j = lane & 15;
    float w[8];
    if (has_ef) {
#pragma unroll
        for (int k = 0; k < 8; ++k) w[k] = Wf[k * 16 + j];
    }
    const int wid = (blockIdx.x * 256 + threadIdx.x) >> 6;
    const int n = (wid << 2) + g;
    const int beg = rowptr[n], end = rowptr[n + 1];
    const float b = Bp[n * 16 + j];
    const uint4* ef4 = reinterpret_cast<const uint4*>(efp);
    float acc = 0.f;
    int s_nxt = (beg + 1 < end) ? srcp[beg + 1] : 0;
    float av = (beg < end) ? G[srcp[beg] * 16 + j] : 0.f;
    for (int pos = beg; pos < end; ++pos) {
        float avc = av;
        int s_nn = (pos + 2 < end) ? srcp[pos + 2] : 0;
        if (pos + 1 < end) av = G[s_nxt * 16 + j];
        s_nxt = s_nn;
        float m = avc + b;
        if (has_ef) {
            uint4 ev = ef4[(size_t)pos];
            m = fmaf(lo16(ev.x), w[0], m);
            m = fmaf(hi16(ev.x), w[1], m);
            m = fmaf(lo16(ev.y), w[2], m);
            m = fmaf(hi16(ev.y), w[3], m);
            m = fmaf(lo16(ev.z), w[4], m);
            m = fmaf(hi16(ev.z), w[5], m);
            m = fmaf(lo16(ev.w), w[6], m);
            m = fmaf(hi16(ev.w), w[7], m);
        }
        acc += fmaxf(m, 0.f);
    }
    if (pout) pout[n * 16 + j] = acc;
    if (has_epi) {
        float pe = ApN[n * 16 + j];
        const int gbase = lane & 48;
#pragma unroll
        for (int k = 0; k < 16; ++k) {
            float pk = __shfl(acc, gbase + k);
            pe = fmaf(pk, WeN[k * 16 + j], pe);
        }
        PeSN[n * 16 + j] = pe;
    }
}

extern "C" void kernel_launch(void* const* d_in, const int* in_sizes, int n_in,
                              void* d_out, int out_size, void* d_ws, size_t ws_size,
                              hipStream_t stream) {
    (void)in_sizes; (void)n_in; (void)out_size;
    const float* inputs = (const float*)d_in[0];
    const float* e_feats = (const float*)d_in[1];
    const float* rain0 = (const float*)d_in[2];
    const int* src = (const int*)d_in[3];
    const int* dst = (const int*)d_in[4];
    const float* W_emb = (const float*)d_in[5];
    const float* Win_hs = (const float*)d_in[6];
    const float* Win_hd = (const float*)d_in[7];
    const float* Win_e = (const float*)d_in[8];
    const float* Win_r = (const float*)d_in[9];
    const float* Wp_hs = (const float*)d_in[10];
    const float* Wp_hd = (const float*)d_in[11];
    const float* Wp_e = (const float*)d_in[12];
    const float* Wp_r = (const float*)d_in[13];
    const float* Wo_hs = (const float*)d_in[14];
    const float* Wo_hd = (const float*)d_in[15];
    const float* Wo_e = (const float*)d_in[16];
    const float* Wo_r = (const float*)d_in[17];
    const float* W_rain = (const float*)d_in[18];
    float* out = (float*)d_out;

    const size_t NF64 = (size_t)NN * 64;
    const size_t NF16 = (size_t)NN * 16;
    const size_t EF = (size_t)NE * 8;

    char* base = (char*)d_ws;
    auto alloc = [&](size_t bytes) -> char* {
        char* p = base;
        base += (bytes + 255) & ~(size_t)255;
        return p;
    };

    const size_t fixed = 5 * NF64 * 2 + 7 * NF16 * 4 +
                         (2 * (size_t)NE + 3 * (size_t)NN + 200) * 4 + 64 * 256;
    const bool big = ws_size >= fixed + 4 * EF * 2;

    u16 *A16, *B16, *aggA16, *aggB16, *aggO16, *efp16;
    float *Ap0, *Bp0, *Ap1, *Bp1, *PeSa, *PeSb, *pbuf, *Wfold;
    A16 = (u16*)alloc(NF64 * 2);
    B16 = (u16*)alloc(NF64 * 2);
    aggA16 = (u16*)alloc(NF64 * 2);
    aggB16 = (u16*)alloc(NF64 * 2);
    aggO16 = (u16*)alloc(NF64 * 2);
    Ap0 = (float*)alloc(NF16 * 4);
    Bp0 = (float*)alloc(NF16 * 4);
    Ap1 = (float*)alloc(NF16 * 4);
    Bp1 = (float*)alloc(NF16 * 4);
    PeSa = (float*)alloc(NF16 * 4);
    PeSb = (float*)alloc(NF16 * 4);
    pbuf = (float*)alloc(NF16 * 4);
    Wfold = (float*)alloc(128 * 4);
    efp16 = (u16*)alloc((big ? 4 * EF : EF) * 2);
    int* srcp = (int*)alloc(NE * 4);
    int* perm = (int*)alloc(NE * 4);
    int* rowptr = (int*)alloc((NN + 1) * 4);
    int* deg = (int*)alloc(NN * 4);
    int* cursor = (int*)alloc(NN * 4);
    int* bsum = (int*)alloc(64 * 4);
    int* boff = (int*)alloc(64 * 4);
    u16* hemb = aggO16;  // safe alias: aggO16 written only at end of t=0

    // ---- CSR build (once) ----
    hipMemsetAsync(deg, 0, NN * sizeof(int), stream);
    hist_kernel<<<(NE + 255) / 256, 256, 0, stream>>>(dst, deg);
    scan1_kernel<<<NBLK_SCAN, 256, 0, stream>>>(deg, bsum);
    scan2_kernel<<<1, 64, 0, stream>>>(bsum, boff, rowptr);
    scan3_kernel<<<NBLK_SCAN, 256, 0, stream>>>(deg, boff, rowptr, cursor);
    scatter_kernel<<<(NE + 255) / 256, 256, 0, stream>>>(src, dst, cursor, perm, srcp);
    if (big)
        efperm_all_kernel<<<(NE + 255) / 256, 256, 0, stream>>>(e_feats, perm, efp16);

    emb_kernel<<<(NN * 64 + 255) / 256, 256, 0, stream>>>(inputs, W_emb, hemb);
    wfold_kernel<<<1, 128, 0, stream>>>(Wp_e, Wfold);

    for (int t = 0; t < TT; ++t) {
        const float* rain = rain0 + t;
        const u16* eft = big ? (efp16 + (size_t)t * EF) : efp16;
        if (!big)
            efperm_one_kernel<<<(NE * 8 + 255) / 256, 256, 0, stream>>>(e_feats, perm, t, efp16);

        // ---- IN s=0 ----
        node_ab_kernel<<<1250, 256, 64 * 64 * 2 * sizeof(float), stream>>>(
            aggO16, (t > 0) ? 1 : 0, nullptr, 0,
            Win_hs, Win_hd, rain, Win_r, A16, B16);
        edge64_csr<<<10000, 256, 0, stream>>>(A16, B16, eft, Win_e, rowptr, srcp, aggA16,
                                              nullptr, nullptr, 0);

        // ---- IN s=1 ----
        node_ab_kernel<<<1250, 256, 64 * 64 * 2 * sizeof(float), stream>>>(
            aggA16, 1, nullptr, 0, Win_hs + 4096, Win_hd + 4096, rain, Win_r + 64, A16, B16);
        edge64_csr<<<10000, 256, 0, stream>>>(A16, B16, eft, Win_e + 512, rowptr, srcp, aggB16,
                                              nullptr, nullptr, 0);

        // ---- PROP: p-independent node parts for both s in one pass ----
        node_p_all<<<625, 256, 0, stream>>>(aggB16, Wp_hs, Wp_hd, rain, Wp_r,
                                            Ap0, Bp0, Ap1, Bp1);

        if (t == 0) {
            edge16_csr<<<2500, 256, 0, stream>>>(Ap0, Bp0, eft, Wfold, 1,
                                                 Ap0, Wp_e, PeSa, 1,
                                                 rowptr, srcp, nullptr);
            edge16_csr<<<2500, 256, 0, stream>>>(PeSa, Bp0, nullptr, nullptr, 0,
                                                 Ap1, Wp_e + 256, PeSb, 1,
                                                 rowptr, srcp, nullptr);
            edge16_csr<<<2500, 256, 0, stream>>>(PeSb, Bp1, nullptr, nullptr, 0,
                                                 nullptr, nullptr, nullptr, 0,
                                                 rowptr, srcp, pbuf);
        } else {
            edge16_csr<<<2500, 256, 0, stream>>>(Ap0, Bp0, eft, Wfold, 1,
                                                 Ap1, Wp_e + 256, PeSa, 1,
                                                 rowptr, srcp, nullptr);
            edge16_csr<<<2500, 256, 0, stream>>>(PeSa, Bp1, nullptr, nullptr, 0,
                                                 nullptr, nullptr, nullptr, 0,
                                                 rowptr, srcp, pbuf);
        }

        // ---- OUT layer (fused rain-output epilogue) ----
        node_ab_kernel<<<1250, 256, 80 * 64 * 2 * sizeof(float), stream>>>(
            aggB16, 1, pbuf, 16, Wo_hs, Wo_hd, rain, Wo_r, A16, B16);
        edge64_csr<<<10000, 256, 0, stream>>>(A16, B16, eft, Wo_e, rowptr, srcp, aggO16,
                                              W_rain, out, t);
    }
}